// Round 1
// baseline (1938.298 us; speedup 1.0000x reference)
//
#include <hip/hip_runtime.h>

#define NN 100000
#define NE 1600000
#define F_IN 165
#define HDIM 128
#define SCAN_BS 1024

static inline int ceil_div(int a, int b) { return (a + b - 1) / b; }

// ---------------- CSR build ----------------

__global__ void count_deg(const int* __restrict__ dst, int* __restrict__ deg, int E) {
    int e = blockIdx.x * blockDim.x + threadIdx.x;
    if (e < E) atomicAdd(&deg[dst[e]], 1);
}

__global__ void scan_block(const int* __restrict__ deg, int* __restrict__ rowptr,
                           int* __restrict__ partials, int n) {
    __shared__ int s[SCAN_BS];
    int t = threadIdx.x;
    int i = blockIdx.x * SCAN_BS + t;
    int v = (i < n) ? deg[i] : 0;
    s[t] = v;
    __syncthreads();
    for (int off = 1; off < SCAN_BS; off <<= 1) {
        int add = (t >= off) ? s[t - off] : 0;
        __syncthreads();
        s[t] += add;
        __syncthreads();
    }
    if (i < n) rowptr[i] = s[t] - v;      // block-local exclusive
    if (t == SCAN_BS - 1) partials[blockIdx.x] = s[SCAN_BS - 1];
}

__global__ void scan_partials(int* partials, int nb) {
    if (blockIdx.x == 0 && threadIdx.x == 0) {
        int run = 0;
        for (int b = 0; b < nb; b++) { int t = partials[b]; partials[b] = run; run += t; }
    }
}

__global__ void add_offsets(int* __restrict__ rowptr, const int* __restrict__ partials,
                            int n, int total) {
    int i = blockIdx.x * blockDim.x + threadIdx.x;
    if (i < n) rowptr[i] += partials[i >> 10];
    if (i == 0) rowptr[n] = total;
}

__global__ void copy_cursor(const int* __restrict__ rowptr, int* __restrict__ cursor, int n) {
    int i = blockIdx.x * blockDim.x + threadIdx.x;
    if (i < n) cursor[i] = rowptr[i];
}

__global__ void fill_col(const int* __restrict__ src, const int* __restrict__ dst,
                         int* __restrict__ cursor, int* __restrict__ col, int E) {
    int e = blockIdx.x * blockDim.x + threadIdx.x;
    if (e < E) {
        int d = dst[e];
        int pos = atomicAdd(&cursor[d], 1);
        col[pos] = src[e];
    }
}

// ---------------- tall-skinny GEMM: Y[N,128] = X[N,K] @ W[128,K]^T (+bias) ----------------
// block = 256 threads, computes 16 rows x 64 output cols (blockIdx.y selects col half)

__global__ __launch_bounds__(256) void gemm_t(const float* __restrict__ X,
                                              const float* __restrict__ W,
                                              const float* __restrict__ bias,
                                              float* __restrict__ Y, int n, int K) {
    const int Kst = K | 1;  // odd stride -> conflict-free LDS
    extern __shared__ float lds[];
    float* Ws = lds;              // 64 * Kst
    float* Hs = lds + 64 * Kst;   // 16 * Kst
    const int tid = threadIdx.x;
    const int row0 = blockIdx.x * 16;
    const int ohalf = blockIdx.y * 64;

    for (int idx = tid; idx < 64 * K; idx += 256) {
        int oo = idx / K, kk = idx - oo * K;
        Ws[oo * Kst + kk] = W[(ohalf + oo) * K + kk];
    }
    for (int idx = tid; idx < 16 * K; idx += 256) {
        int r = idx / K, k = idx - r * K;
        int row = row0 + r;
        Hs[r * Kst + k] = (row < n) ? X[(size_t)row * K + k] : 0.f;
    }
    __syncthreads();

    const int oo = tid & 63;
    const int rbase = (tid >> 6) * 4;
    float a0 = 0.f, a1 = 0.f, a2 = 0.f, a3 = 0.f;
    const float* wrow = &Ws[oo * Kst];
    const float* h0 = &Hs[(rbase + 0) * Kst];
    const float* h1 = &Hs[(rbase + 1) * Kst];
    const float* h2 = &Hs[(rbase + 2) * Kst];
    const float* h3 = &Hs[(rbase + 3) * Kst];
    for (int k = 0; k < K; k++) {
        float w = wrow[k];
        a0 += h0[k] * w; a1 += h1[k] * w; a2 += h2[k] * w; a3 += h3[k] * w;
    }
    const int ocol = ohalf + oo;
    float b = bias ? bias[ocol] : 0.f;
    float acc[4] = {a0, a1, a2, a3};
#pragma unroll
    for (int rr = 0; rr < 4; rr++) {
        int row = row0 + rbase + rr;
        if (row < n) Y[(size_t)row * HDIM + ocol] = acc[rr] + b;
    }
}

// ---------------- aggregation + epilogue ----------------
// MODE 0: h = relu(mean + q)                       -> hout
// MODE 1: h = relu(LN(mean + q + hres))            -> hout
// MODE 2: as MODE 1, then out[i,:] = h @ Wlin^T + blin (no hout write)

template <int MODE>
__global__ __launch_bounds__(128) void aggregate_k(
    const float* __restrict__ p, const float* __restrict__ q,
    const float* __restrict__ hres, float* __restrict__ hout,
    const int* __restrict__ rowptr, const int* __restrict__ col,
    const float* __restrict__ Wlin, const float* __restrict__ blin,
    float* __restrict__ out) {
    const int i = blockIdx.x;
    const int f = threadIdx.x;
    __shared__ int cbuf[128];
    __shared__ float red[2];

    const int beg = rowptr[i], end = rowptr[i + 1];
    float acc = 0.f;
    for (int base = beg; base < end; base += 128) {
        int m = min(128, end - base);
        if (f < m) cbuf[f] = col[base + f];
        __syncthreads();
        for (int j = 0; j < m; j++) acc += p[(size_t)cbuf[j] * HDIM + f];
        __syncthreads();
    }

    float degf = (float)(end - beg);
    float v = acc / fmaxf(degf, 1.f) + q[(size_t)i * HDIM + f];

    const int lane = f & 63, wid = f >> 6;
    auto blockSum = [&](float x) -> float {
        for (int off = 32; off > 0; off >>= 1) x += __shfl_down(x, off, 64);
        if (lane == 0) red[wid] = x;
        __syncthreads();
        float tot = red[0] + red[1];
        __syncthreads();
        return tot;
    };

    if (MODE == 0) {
        hout[(size_t)i * HDIM + f] = fmaxf(v, 0.f);
        return;
    }

    v += hres[(size_t)i * HDIM + f];
    float mu = blockSum(v) * (1.f / HDIM);
    float d = v - mu;
    float var = blockSum(d * d) * (1.f / HDIM);
    float h = fmaxf(d * rsqrtf(var + 1e-5f), 0.f);

    if (MODE == 1) {
        hout[(size_t)i * HDIM + f] = h;
    } else {
        float s0 = blockSum(h * Wlin[f]);
        float s1 = blockSum(h * Wlin[HDIM + f]);
        if (f == 0) {
            out[(size_t)i * 2 + 0] = s0 + blin[0];
            out[(size_t)i * 2 + 1] = s1 + blin[1];
        }
    }
}

// ---------------- launch ----------------

extern "C" void kernel_launch(void* const* d_in, const int* in_sizes, int n_in,
                              void* d_out, int out_size, void* d_ws, size_t ws_size,
                              hipStream_t stream) {
    const float* x = (const float*)d_in[0];
    const int* ei = (const int*)d_in[1];
    const int* srcI = ei;
    const int* dstI = ei + NE;
    const float* Wl0 = (const float*)d_in[2];
    const float* bl0 = (const float*)d_in[3];
    const float* Wr0 = (const float*)d_in[4];
    const float* Wl1 = (const float*)d_in[5];
    const float* bl1 = (const float*)d_in[6];
    const float* Wr1 = (const float*)d_in[7];
    const float* Wl2 = (const float*)d_in[8];
    const float* bl2 = (const float*)d_in[9];
    const float* Wr2 = (const float*)d_in[10];
    const float* Wlin = (const float*)d_in[11];
    const float* blin = (const float*)d_in[12];
    float* out = (float*)d_out;

    // workspace carve (all 4-byte aligned)
    char* w = (char*)d_ws;
    float* p = (float*)w;  w += (size_t)NN * HDIM * 4;
    float* A = (float*)w;  w += (size_t)NN * HDIM * 4;
    float* B = (float*)w;  w += (size_t)NN * HDIM * 4;
    int* deg = (int*)w;     w += (size_t)NN * 4;
    int* rowptr = (int*)w;  w += (size_t)(NN + 1) * 4;
    int* cursor = (int*)w;  w += (size_t)NN * 4;
    int* colA = (int*)w;    w += (size_t)NE * 4;
    int* partials = (int*)w;

    const int NB = ceil_div(NN, SCAN_BS);

    // CSR build
    hipMemsetAsync(deg, 0, (size_t)NN * 4, stream);
    count_deg<<<ceil_div(NE, 256), 256, 0, stream>>>(dstI, deg, NE);
    scan_block<<<NB, SCAN_BS, 0, stream>>>(deg, rowptr, partials, NN);
    scan_partials<<<1, 1, 0, stream>>>(partials, NB);
    add_offsets<<<ceil_div(NN, 256), 256, 0, stream>>>(rowptr, partials, NN, NE);
    copy_cursor<<<ceil_div(NN, 256), 256, 0, stream>>>(rowptr, cursor, NN);
    fill_col<<<ceil_div(NE, 256), 256, 0, stream>>>(srcI, dstI, cursor, colA, NE);

    dim3 gemm_grid(ceil_div(NN, 16), 2);
    size_t lds165 = (size_t)80 * (F_IN | 1) * 4;
    size_t lds128 = (size_t)80 * (HDIM | 1) * 4;

    // layer 0: p = x@Wl0^T ; A = x@Wr0^T + bl0 ; h0 = relu(mean_p + A) -> A (in place)
    gemm_t<<<gemm_grid, 256, lds165, stream>>>(x, Wl0, nullptr, p, NN, F_IN);
    gemm_t<<<gemm_grid, 256, lds165, stream>>>(x, Wr0, bl0, A, NN, F_IN);
    aggregate_k<0><<<NN, 128, 0, stream>>>(p, A, nullptr, A, rowptr, colA, nullptr, nullptr, nullptr);

    // layer 1: p = A@Wl1^T ; B = A@Wr1^T + bl1 ; h1 = relu(LN(mean_p + B + A)) -> B
    gemm_t<<<gemm_grid, 256, lds128, stream>>>(A, Wl1, nullptr, p, NN, HDIM);
    gemm_t<<<gemm_grid, 256, lds128, stream>>>(A, Wr1, bl1, B, NN, HDIM);
    aggregate_k<1><<<NN, 128, 0, stream>>>(p, B, A, B, rowptr, colA, nullptr, nullptr, nullptr);

    // layer 2 + final: p = B@Wl2^T ; A = B@Wr2^T + bl2 ; out = relu(LN(mean_p + A + B)) @ Wlin^T + blin
    gemm_t<<<gemm_grid, 256, lds128, stream>>>(B, Wl2, nullptr, p, NN, HDIM);
    gemm_t<<<gemm_grid, 256, lds128, stream>>>(B, Wr2, bl2, A, NN, HDIM);
    aggregate_k<2><<<NN, 128, 0, stream>>>(p, A, B, nullptr, rowptr, colA, Wlin, blin, out);
}

// Round 2
// 765.666 us; speedup vs baseline: 2.5315x; 2.5315x over previous
//
#include <hip/hip_runtime.h>

#define NN 100000
#define NE 1600000
#define F_IN 165
#define KP0 192       // F_IN padded to multiple of 32
#define HDIM 128
#define SCAN_BS 1024
#define BM 128
#define BK 32
#define LDT 40        // LDS row stride in bf16 elems (80B: 16B-aligned, 2-way-max bank alias)

typedef float f32x4 __attribute__((ext_vector_type(4)));
typedef __bf16 bf16x8 __attribute__((ext_vector_type(8)));

static inline int ceil_div(int a, int b) { return (a + b - 1) / b; }

__device__ inline unsigned short f2bf(float f) {
    union { float f; unsigned u; } c; c.f = f;
    unsigned u = c.u;
    u += 0x7FFFu + ((u >> 16) & 1u);   // round-to-nearest-even
    return (unsigned short)(u >> 16);
}
__device__ inline float bf2f(unsigned short s) {
    union { unsigned u; float f; } c; c.u = ((unsigned)s) << 16;
    return c.f;
}

// ---------------- CSR build ----------------

__global__ void count_deg(const int* __restrict__ dst, int* __restrict__ deg, int E) {
    int e = blockIdx.x * blockDim.x + threadIdx.x;
    if (e < E) atomicAdd(&deg[dst[e]], 1);
}

__global__ void scan_block(const int* __restrict__ deg, int* __restrict__ rowptr,
                           int* __restrict__ partials, int n) {
    __shared__ int s[SCAN_BS];
    int t = threadIdx.x;
    int i = blockIdx.x * SCAN_BS + t;
    int v = (i < n) ? deg[i] : 0;
    s[t] = v;
    __syncthreads();
    for (int off = 1; off < SCAN_BS; off <<= 1) {
        int add = (t >= off) ? s[t - off] : 0;
        __syncthreads();
        s[t] += add;
        __syncthreads();
    }
    if (i < n) rowptr[i] = s[t] - v;
    if (t == SCAN_BS - 1) partials[blockIdx.x] = s[SCAN_BS - 1];
}

__global__ void scan_partials(int* partials, int nb) {
    if (blockIdx.x == 0 && threadIdx.x == 0) {
        int run = 0;
        for (int b = 0; b < nb; b++) { int t = partials[b]; partials[b] = run; run += t; }
    }
}

__global__ void add_offsets(int* __restrict__ rowptr, const int* __restrict__ partials,
                            int n, int total) {
    int i = blockIdx.x * blockDim.x + threadIdx.x;
    if (i < n) rowptr[i] += partials[i >> 10];
    if (i == 0) rowptr[n] = total;
}

__global__ void copy_cursor(const int* __restrict__ rowptr, int* __restrict__ cursor, int n) {
    int i = blockIdx.x * blockDim.x + threadIdx.x;
    if (i < n) cursor[i] = rowptr[i];
}

__global__ void fill_col(const int* __restrict__ src, const int* __restrict__ dst,
                         int* __restrict__ cursor, int* __restrict__ col, int E) {
    int e = blockIdx.x * blockDim.x + threadIdx.x;
    if (e < E) {
        int d = dst[e];
        int pos = atomicAdd(&cursor[d], 1);
        col[pos] = src[e];
    }
}

// ---------------- conversions ----------------

__global__ void convert_x(const float* __restrict__ x, unsigned short* __restrict__ xb) {
    int row = blockIdx.x, k = threadIdx.x;  // 192 threads
    xb[(size_t)row * KP0 + k] = (k < F_IN) ? f2bf(x[(size_t)row * F_IN + k]) : (unsigned short)0;
}

__global__ void convert_w(const float* __restrict__ Wl0, const float* __restrict__ Wr0,
                          const float* __restrict__ Wl1, const float* __restrict__ Wr1,
                          const float* __restrict__ Wl2, const float* __restrict__ Wr2,
                          unsigned short* __restrict__ wb) {
    int w = blockIdx.x >> 7, row = blockIdx.x & 127, k = threadIdx.x;  // 192 threads
    if (w < 2) {
        const float* W = w ? Wr0 : Wl0;
        wb[(size_t)w * 128 * KP0 + row * KP0 + k] =
            (k < F_IN) ? f2bf(W[row * F_IN + k]) : (unsigned short)0;
    } else if (k < HDIM) {
        const float* W = (w == 2) ? Wl1 : (w == 3) ? Wr1 : (w == 4) ? Wl2 : Wr2;
        wb[(size_t)2 * 128 * KP0 + (size_t)(w - 2) * 128 * HDIM + row * HDIM + k] =
            f2bf(W[row * HDIM + k]);
    }
}

// ---------------- MFMA GEMM: Y[n,128] = Xb[n,Kp] @ Wb[128,Kp]^T (+bias) ----------------
// 256 threads = 4 waves; block tile 128 rows x 128 cols; wave = 32 rows x 128 cols.
// OUTBF: write bf16 (for p, the gather source), else f32.

template <bool OUTBF>
__global__ __launch_bounds__(256) void gemm_mfma(
    const unsigned short* __restrict__ Xb, const unsigned short* __restrict__ Wb,
    const float* __restrict__ bias, void* __restrict__ Yv, int n, int Kp) {
    __shared__ __bf16 As[BM * LDT];
    __shared__ __bf16 Ws[HDIM * LDT];
    const int tid = threadIdx.x;
    const int lane = tid & 63;
    const int wv = tid >> 6;
    const int row0 = blockIdx.x * BM;
    const int wrow0 = wv * 32;
    const int lr = lane & 15;          // frag row (A) / col (B,D)
    const int kl = (lane >> 4) * 8;    // frag k offset within chunk

    f32x4 acc[2][8] = {};

    for (int k0 = 0; k0 < Kp; k0 += BK) {
        // stage A tile: 128 rows x 32 k -> 512 segs of 16B, 2 iters x 256 thr
#pragma unroll
        for (int i = 0; i < 2; i++) {
            int seg = i * 256 + tid;
            int r = seg >> 2, ks = (seg & 3) * 8;
            int4 v = {0, 0, 0, 0};
            int grow = row0 + r;
            if (grow < n) v = *(const int4*)&Xb[(size_t)grow * Kp + k0 + ks];
            *(int4*)&As[r * LDT + ks] = v;
        }
        // stage W tile: 128 cols x 32 k
#pragma unroll
        for (int i = 0; i < 2; i++) {
            int seg = i * 256 + tid;
            int r = seg >> 2, ks = (seg & 3) * 8;
            *(int4*)&Ws[r * LDT + ks] = *(const int4*)&Wb[(size_t)r * Kp + k0 + ks];
        }
        __syncthreads();
        bf16x8 af0 = *(const bf16x8*)&As[(wrow0 + lr) * LDT + kl];
        bf16x8 af1 = *(const bf16x8*)&As[(wrow0 + 16 + lr) * LDT + kl];
#pragma unroll
        for (int ct = 0; ct < 8; ct++) {
            bf16x8 bv = *(const bf16x8*)&Ws[(ct * 16 + lr) * LDT + kl];
            acc[0][ct] = __builtin_amdgcn_mfma_f32_16x16x32_bf16(af0, bv, acc[0][ct], 0, 0, 0);
            acc[1][ct] = __builtin_amdgcn_mfma_f32_16x16x32_bf16(af1, bv, acc[1][ct], 0, 0, 0);
        }
        __syncthreads();
    }

    // epilogue: D[row][col], col = lane&15, row = (lane>>4)*4 + r   [m89-verified]
#pragma unroll
    for (int rt = 0; rt < 2; rt++) {
#pragma unroll
        for (int ct = 0; ct < 8; ct++) {
            int col = ct * 16 + lr;
            float b = bias ? bias[col] : 0.f;
#pragma unroll
            for (int r = 0; r < 4; r++) {
                int row = row0 + wrow0 + rt * 16 + (lane >> 4) * 4 + r;
                if (row < n) {
                    float v = acc[rt][ct][r] + b;
                    if (OUTBF) ((unsigned short*)Yv)[(size_t)row * HDIM + col] = f2bf(v);
                    else       ((float*)Yv)[(size_t)row * HDIM + col] = v;
                }
            }
        }
    }
}

// ---------------- aggregation + epilogue ----------------
// MODE 0: h = relu(mean_p + q)                    -> hout (bf16)
// MODE 1: h = relu(LN(mean_p + q + hres))         -> hout (bf16)
// MODE 2: as MODE 1, then out = h @ Wlin^T + blin (f32, no hout)

template <int MODE>
__global__ __launch_bounds__(128) void aggregate_k(
    const unsigned short* __restrict__ p, const float* __restrict__ q,
    const unsigned short* __restrict__ hres, unsigned short* __restrict__ hout,
    const int* __restrict__ rowptr, const int* __restrict__ col,
    const float* __restrict__ Wlin, const float* __restrict__ blin,
    float* __restrict__ out) {
    const int i = blockIdx.x;
    const int f = threadIdx.x;
    __shared__ int cbuf[128];
    __shared__ float red[2];

    const int beg = rowptr[i], end = rowptr[i + 1];
    float acc = 0.f;
    for (int base = beg; base < end; base += 128) {
        int m = min(128, end - base);
        if (f < m) cbuf[f] = col[base + f];
        __syncthreads();
        for (int j = 0; j < m; j++) acc += bf2f(p[(size_t)cbuf[j] * HDIM + f]);
        __syncthreads();
    }

    float degf = (float)(end - beg);
    float v = acc / fmaxf(degf, 1.f) + q[(size_t)i * HDIM + f];

    const int lane = f & 63, wid = f >> 6;
    auto blockSum = [&](float x) -> float {
        for (int off = 32; off > 0; off >>= 1) x += __shfl_down(x, off, 64);
        if (lane == 0) red[wid] = x;
        __syncthreads();
        float tot = red[0] + red[1];
        __syncthreads();
        return tot;
    };

    if (MODE == 0) {
        hout[(size_t)i * HDIM + f] = f2bf(fmaxf(v, 0.f));
        return;
    }

    v += bf2f(hres[(size_t)i * HDIM + f]);
    float mu = blockSum(v) * (1.f / HDIM);
    float d = v - mu;
    float var = blockSum(d * d) * (1.f / HDIM);
    float h = fmaxf(d * rsqrtf(var + 1e-5f), 0.f);

    if (MODE == 1) {
        hout[(size_t)i * HDIM + f] = f2bf(h);
    } else {
        float s0 = blockSum(h * Wlin[f]);
        float s1 = blockSum(h * Wlin[HDIM + f]);
        if (f == 0) {
            out[(size_t)i * 2 + 0] = s0 + blin[0];
            out[(size_t)i * 2 + 1] = s1 + blin[1];
        }
    }
}

// ---------------- launch ----------------

static inline size_t rnd(size_t x) { return (x + 255) & ~(size_t)255; }

extern "C" void kernel_launch(void* const* d_in, const int* in_sizes, int n_in,
                              void* d_out, int out_size, void* d_ws, size_t ws_size,
                              hipStream_t stream) {
    const float* x = (const float*)d_in[0];
    const int* ei = (const int*)d_in[1];
    const int* srcI = ei;
    const int* dstI = ei + NE;
    const float* Wl0 = (const float*)d_in[2];
    const float* bl0 = (const float*)d_in[3];
    const float* Wr0 = (const float*)d_in[4];
    const float* Wl1 = (const float*)d_in[5];
    const float* bl1 = (const float*)d_in[6];
    const float* Wr1 = (const float*)d_in[7];
    const float* Wl2 = (const float*)d_in[8];
    const float* bl2 = (const float*)d_in[9];
    const float* Wr2 = (const float*)d_in[10];
    const float* Wlin = (const float*)d_in[11];
    const float* blin = (const float*)d_in[12];
    float* out = (float*)d_out;

    // workspace carve (256B-aligned chunks)
    char* w = (char*)d_ws;
    unsigned short* p = (unsigned short*)w;     w += rnd((size_t)NN * HDIM * 2);
    float* q = (float*)w;                       w += rnd((size_t)NN * HDIM * 4);
    unsigned short* hbfA = (unsigned short*)w;  w += rnd((size_t)NN * KP0 * 2);  // x-bf16, then h0
    unsigned short* hbfB = (unsigned short*)w;  w += rnd((size_t)NN * HDIM * 2); // h1
    unsigned short* wbf = (unsigned short*)w;   w += rnd((size_t)(2 * 128 * KP0 + 4 * 128 * HDIM) * 2);
    int* deg = (int*)w;     w += rnd((size_t)NN * 4);
    int* rowptr = (int*)w;  w += rnd((size_t)(NN + 1) * 4);
    int* cursor = (int*)w;  w += rnd((size_t)NN * 4);
    int* colA = (int*)w;    w += rnd((size_t)NE * 4);
    int* partials = (int*)w;

    const int NB = ceil_div(NN, SCAN_BS);

    // CSR build
    hipMemsetAsync(deg, 0, (size_t)NN * 4, stream);
    count_deg<<<ceil_div(NE, 256), 256, 0, stream>>>(dstI, deg, NE);
    scan_block<<<NB, SCAN_BS, 0, stream>>>(deg, rowptr, partials, NN);
    scan_partials<<<1, 1, 0, stream>>>(partials, NB);
    add_offsets<<<ceil_div(NN, 256), 256, 0, stream>>>(rowptr, partials, NN, NE);
    copy_cursor<<<ceil_div(NN, 256), 256, 0, stream>>>(rowptr, cursor, NN);
    fill_col<<<ceil_div(NE, 256), 256, 0, stream>>>(srcI, dstI, cursor, colA, NE);

    // dtype conversions
    convert_w<<<6 * 128, 192, 0, stream>>>(Wl0, Wr0, Wl1, Wr1, Wl2, Wr2, wbf);
    convert_x<<<NN, 192, 0, stream>>>(x, hbfA);

    const unsigned short* wWl0 = wbf;
    const unsigned short* wWr0 = wbf + (size_t)128 * KP0;
    const unsigned short* wWl1 = wbf + (size_t)2 * 128 * KP0;
    const unsigned short* wWr1 = wWl1 + (size_t)128 * HDIM;
    const unsigned short* wWl2 = wWr1 + (size_t)128 * HDIM;
    const unsigned short* wWr2 = wWl2 + (size_t)128 * HDIM;

    const int GB = ceil_div(NN, BM);

    // layer 0: p = x@Wl0^T (bf16) ; q = x@Wr0^T + bl0 (f32) ; h0 = relu(mean_p + q) -> hbfA
    gemm_mfma<true><<<GB, 256, 0, stream>>>(hbfA, wWl0, nullptr, p, NN, KP0);
    gemm_mfma<false><<<GB, 256, 0, stream>>>(hbfA, wWr0, bl0, q, NN, KP0);
    aggregate_k<0><<<NN, 128, 0, stream>>>(p, q, nullptr, hbfA, rowptr, colA, nullptr, nullptr, nullptr);

    // layer 1: h1 = relu(LN(mean_p + q + h0)) -> hbfB
    gemm_mfma<true><<<GB, 256, 0, stream>>>(hbfA, wWl1, nullptr, p, NN, HDIM);
    gemm_mfma<false><<<GB, 256, 0, stream>>>(hbfA, wWr1, bl1, q, NN, HDIM);
    aggregate_k<1><<<NN, 128, 0, stream>>>(p, q, hbfA, hbfB, rowptr, colA, nullptr, nullptr, nullptr);

    // layer 2 + final proj
    gemm_mfma<true><<<GB, 256, 0, stream>>>(hbfB, wWl2, nullptr, p, NN, HDIM);
    gemm_mfma<false><<<GB, 256, 0, stream>>>(hbfB, wWr2, bl2, q, NN, HDIM);
    aggregate_k<2><<<NN, 128, 0, stream>>>(p, q, hbfB, nullptr, rowptr, colA, Wlin, blin, out);
}